// Round 7
// baseline (41.244 us; speedup 1.0000x reference)
//
#include <hip/hip_runtime.h>
#include <math.h>

#define NQ 8
#define DEPTH 3
#define FDIM 16
#define HDIM 256
#define WAVES_PER_BLOCK 4
#define THREADS (WAVES_PER_BLOCK * 64)
#define NGATE (NQ * DEPTH)        // 24 (RZ,RY) pairs

// ---------------- cross-lane xor shuffles ----------------
template<int CTRL>
__device__ __forceinline__ float dpp1(float v) {
    return __int_as_float(__builtin_amdgcn_update_dpp(
        0, __float_as_int(v), CTRL, 0xF, 0xF, true));
}

// single-DPP xor masks used by wred (VALU, lowest latency)
template<int M4>
__device__ __forceinline__ float shuf4(float v) {
    if constexpr (M4 == 1)  return dpp1<0xB1>(v);   // quad_perm xor1
    else if constexpr (M4 == 2)  return dpp1<0x4E>(v);   // quad_perm xor2
    else if constexpr (M4 == 4)  return dpp1<0x1B>(dpp1<0x141>(v)); // xor3 o xor7
    else if constexpr (M4 == 8)  return dpp1<0x128>(v);  // row_ror:8 == xor8
    else return v;
}

// general 6-bit xor shuffle on the LDS pipe (0 VALU slots):
// ds_swizzle BitMode for masks 1..31, ds_bpermute for masks with bit5 set.
template<int ML>
__device__ __forceinline__ float shuf(float v, int lane) {
    if constexpr (ML == 0) {
        return v;
    } else if constexpr (ML >= 32) {
        int addr = (lane ^ ML) << 2;   // CSE'd across the 8 uses per gate
        return __int_as_float(__builtin_amdgcn_ds_bpermute(addr, __float_as_int(v)));
    } else {
        return __int_as_float(__builtin_amdgcn_ds_swizzle(
            __float_as_int(v), (ML << 10) | 0x1F));   // xor=ML, and=0x1F
    }
}

// full 64-lane sum, all lanes receive the total.
// permlane*_swap trick: r[0]+r[1] == v + v[lane^K] for every lane (no select).
__device__ __forceinline__ float wred(float v, int lane) {
    v += shuf4<1>(v);
    v += shuf4<2>(v);
    v += shuf4<4>(v);
    v += shuf4<8>(v);
#if __has_builtin(__builtin_amdgcn_permlane16_swap)
    {
        auto r = __builtin_amdgcn_permlane16_swap(__float_as_int(v), __float_as_int(v), false, false);
        v = __int_as_float(r[0]) + __int_as_float(r[1]);
    }
#else
    v += __shfl_xor(v, 16, 64);
#endif
#if __has_builtin(__builtin_amdgcn_permlane32_swap)
    {
        auto r = __builtin_amdgcn_permlane32_swap(__float_as_int(v), __float_as_int(v), false, false);
        v = __int_as_float(r[0]) + __int_as_float(r[1]);
    }
#else
    v += __shfl_xor(v, 32, 64);
#endif
    return v;
}

__device__ __forceinline__ float fast_tanh(float y) {
    float ex = __expf(2.f * y);                       // inf for large y -> t=1
    return 1.f - 2.f * __builtin_amdgcn_rcpf(ex + 1.f);
}

// ---------------- relabeled gate ----------------
// Physical storage never permuted. Layer-l gates use pair-mask M = A^l*e_b and
// parity row R = row_b(A^{-l}), both 8-bit compile-time constants over
// x = (hi<<6)|lane.  RZ: amp *= (cz + i*sgz), sgz = p? sz : -sz.
// RY: amp = cy*amp + sgy*partner, partner at x ^ M, sgy = p? sy : -sy.
template<int M, int R>
__device__ __forceinline__ void gate2(float (&sr)[4], float (&si)[4],
                                      float cz, float szv, float cy, float sy,
                                      int lane) {
    constexpr int ML = M & 63, MH = (M >> 6) & 3;
    constexpr int RL = R & 63, RH = (R >> 6) & 3;
    bool p0;
    if constexpr (RL == 0)                 p0 = false;
    else if constexpr ((RL & (RL-1)) == 0) p0 = (lane & RL) != 0;
    else                                   p0 = (__popc(lane & RL) & 1) != 0;
    float sgz = p0 ? szv : -szv;
    float sgy = p0 ? sy  : -sy;
    // RZ (diagonal phase)
#pragma unroll
    for (int hi = 0; hi < 4; hi++) {
        const bool f = (__builtin_popcount(hi & RH) & 1) != 0;   // folds per-hi
        float z = f ? -sgz : sgz;
        float nr = fmaf(sr[hi], cz, -(si[hi] * z));
        float ni = fmaf(si[hi], cz,  (sr[hi] * z));
        sr[hi] = nr; si[hi] = ni;
    }
    // RY partners from post-RZ values
    float pr[4], pi[4];
#pragma unroll
    for (int hi = 0; hi < 4; hi++) {
        pr[hi] = shuf<ML>(sr[hi ^ MH], lane);
        pi[hi] = shuf<ML>(si[hi ^ MH], lane);
    }
#pragma unroll
    for (int hi = 0; hi < 4; hi++) {
        const bool f = (__builtin_popcount(hi & RH) & 1) != 0;
        float yv = f ? -sgy : sgy;
        sr[hi] = fmaf(yv, pr[hi], cy * sr[hi]);
        si[hi] = fmaf(yv, pi[hi], cy * si[hi]);
    }
}

__global__ __launch_bounds__(THREADS, 8) void hqcl_kernel(
    const float* __restrict__ x,     // (B,16)
    const float* __restrict__ w1,    // (256,16)
    const float* __restrict__ b1,    // (256)
    const float* __restrict__ w2,    // (8,256)
    const float* __restrict__ b2,    // (8)
    const float* __restrict__ qp,    // (48)
    const float* __restrict__ dw1,   // (256,1)
    const float* __restrict__ db1,   // (256)
    const float* __restrict__ dw2,   // (1,256)
    const float* __restrict__ db2,   // (1)
    float* __restrict__ out, int B)
{
    __shared__ float4 sG4[NGATE];    // (cz,sz,cy,sy) per gate; gate g: qp[2g], qp[2g+1]

    const int t = threadIdx.x;
    if (t < 2 * NGATE) {
        float s, c;
        __sincosf(qp[t] * 0.5f, &s, &c);
        float* p = (float*)&sG4[t >> 1] + 2 * (t & 1);
        p[0] = c; p[1] = s;
    }
    __syncthreads();

    const int lane = t & 63;
    const int row  = blockIdx.x * WAVES_PER_BLOCK + (t >> 6);
    if (row >= B) return;

    // ---- encoder: h = relu(x @ W1^T + b1) ----
    const float4* xp = (const float4*)(x + row * FDIM);
    float4 x0 = xp[0], x1 = xp[1], x2 = xp[2], x3 = xp[3];

    float hreg[4];
#pragma unroll
    for (int m = 0; m < 4; m++) {
        int j = lane + 64 * m;
        const float4* wp = (const float4*)(w1 + j * FDIM);
        float4 wa = wp[0], wb = wp[1], wc = wp[2], wd = wp[3];
        float acc = b1[j];
        acc = fmaf(x0.x, wa.x, acc); acc = fmaf(x0.y, wa.y, acc);
        acc = fmaf(x0.z, wa.z, acc); acc = fmaf(x0.w, wa.w, acc);
        acc = fmaf(x1.x, wb.x, acc); acc = fmaf(x1.y, wb.y, acc);
        acc = fmaf(x1.z, wb.z, acc); acc = fmaf(x1.w, wb.w, acc);
        acc = fmaf(x2.x, wc.x, acc); acc = fmaf(x2.y, wc.y, acc);
        acc = fmaf(x2.z, wc.z, acc); acc = fmaf(x2.w, wc.w, acc);
        acc = fmaf(x3.x, wd.x, acc); acc = fmaf(x3.y, wd.y, acc);
        acc = fmaf(x3.z, wd.z, acc); acc = fmaf(x3.w, wd.w, acc);
        hreg[m] = fmaxf(acc, 0.f);
    }

    // ---- angles = tanh(h @ W2^T + b2) * pi, folded into product state ----
    // angle/2 = tanh*pi/2 rad = tanh/4 revolutions -> native v_sin/v_cos range.
    // Qubits 0,1 (amp bits 7,6) keep sin/cos; qubits 2..7 (lane bits 5..0)
    // fold immediately into running product pl -> only 4+1 live regs, not 16.
    float c00, s00, c01, s01;
    float pl = 1.f;
#pragma unroll
    for (int q = 0; q < NQ; q++) {
        float a = 0.f;
#pragma unroll
        for (int m = 0; m < 4; m++)
            a = fmaf(hreg[m], w2[q * HDIM + lane + 64 * m], a);
        a = wred(a, lane);
        float u = 0.25f * fast_tanh(a + b2[q]);
        float sv, cv;
        asm("v_sin_f32 %0, %1" : "=v"(sv) : "v"(u));
        asm("v_cos_f32 %0, %1" : "=v"(cv) : "v"(u));
        if (q == 0)      { c00 = cv; s00 = sv; }
        else if (q == 1) { c01 = cv; s01 = sv; }
        else             { pl *= ((lane >> (7 - q)) & 1) ? sv : cv; }
    }

    // ---- initial product state: amp x = hi*64 + lane ----
    float sr[4], si[4];
    sr[0] = pl * c01 * c00;
    sr[1] = pl * s01 * c00;
    sr[2] = pl * c01 * s00;
    sr[3] = pl * s01 * s00;
#pragma unroll
    for (int hi = 0; hi < 4; hi++) si[hi] = 0.f;

    // ---- circuit: CX chains folded into per-layer masks (GF(2) relabeling) ----
    // A cols: C1 03 06 0C 18 30 60 C0 ; A^2 cols: 61 C2 05 0A 14 28 50 A0
    // A^-1 rows: FF FE FC F8 F0 E0 C0 7F ; A^-2 rows: AA 55 AB 57 AF 5F BF D5
#define GATE(L, Q, MM, RR) { float4 g4 = sG4[(L)*8 + (Q)]; \
        gate2<MM, RR>(sr, si, g4.x, g4.y, g4.z, g4.w, lane); }
    // layer 0 (identity labeling)
    GATE(0,0,0x80,0x80) GATE(0,1,0x40,0x40) GATE(0,2,0x20,0x20) GATE(0,3,0x10,0x10)
    GATE(0,4,0x08,0x08) GATE(0,5,0x04,0x04) GATE(0,6,0x02,0x02) GATE(0,7,0x01,0x01)
    // layer 1 (masks = cols of A, parities = rows of A^-1)
    GATE(1,0,0xC0,0x7F) GATE(1,1,0x60,0xC0) GATE(1,2,0x30,0xE0) GATE(1,3,0x18,0xF0)
    GATE(1,4,0x0C,0xF8) GATE(1,5,0x06,0xFC) GATE(1,6,0x03,0xFE) GATE(1,7,0xC1,0xFF)
    // layer 2 (masks = cols of A^2, parities = rows of A^-2)
    GATE(2,0,0xA0,0xD5) GATE(2,1,0x50,0xBF) GATE(2,2,0x28,0x5F) GATE(2,3,0x14,0xAF)
    GATE(2,4,0x0A,0x57) GATE(2,5,0x05,0xAB) GATE(2,6,0xC2,0x55) GATE(2,7,0x61,0xAA)
#undef GATE

    // ---- <Z_0> with final labeling: sign = parity(x & 0x4C) (row7 of A^-3) ----
    float m0 = sr[0]*sr[0] + si[0]*si[0] + sr[2]*sr[2] + si[2]*si[2]; // hi&1==0
    float m1 = sr[1]*sr[1] + si[1]*si[1] + sr[3]*sr[3] + si[3]*si[3]; // hi&1==1
    bool pb = (__popc(lane & 0x0C) & 1) != 0;
    float e = pb ? (m1 - m0) : (m0 - m1);
    e = wred(e, lane);

    // ---- decoder ----
    float acc = 0.f;
#pragma unroll
    for (int m = 0; m < 4; m++) {
        int j = lane + 64 * m;
        float d = fmaxf(fmaf(e, dw1[j], db1[j]), 0.f);
        acc = fmaf(d, dw2[j], acc);
    }
    acc = wred(acc, lane);
    if (lane == 0) out[row] = 1.f / (1.f + __expf(-(acc + db2[0])));
}

extern "C" void kernel_launch(void* const* d_in, const int* in_sizes, int n_in,
                              void* d_out, int out_size, void* d_ws, size_t ws_size,
                              hipStream_t stream) {
    const float* x   = (const float*)d_in[0];
    const float* w1  = (const float*)d_in[1];
    const float* b1  = (const float*)d_in[2];
    const float* w2  = (const float*)d_in[3];
    const float* b2  = (const float*)d_in[4];
    const float* qp  = (const float*)d_in[5];
    const float* dw1 = (const float*)d_in[6];
    const float* db1 = (const float*)d_in[7];
    const float* dw2 = (const float*)d_in[8];
    const float* db2 = (const float*)d_in[9];
    float* out = (float*)d_out;

    const int B = in_sizes[0] / FDIM;
    const int grid = (B + WAVES_PER_BLOCK - 1) / WAVES_PER_BLOCK;
    hqcl_kernel<<<grid, THREADS, 0, stream>>>(x, w1, b1, w2, b2, qp, dw1, db1, dw2, db2, out, B);
}